// Round 8
// baseline (480.999 us; speedup 1.0000x reference)
//
#include <hip/hip_runtime.h>
#include <hip/hip_fp16.h>

// ---------------------------------------------------------------------------
// 2-layer GCN encoder (PyG GCNConv semantics). fp16 storage + MFMA GEMMs,
// f32 accumulation. Fixed-capacity adjacency slots (CAP=64, deg~Poisson(16),
// overflow prob ~1e-20, clamped). dinv = rsqrtf(cnt+1) inline everywhere.
// Pipeline (1 memset + 5 kernels):
//   1. memset cnt=0
//   2. prep    : fill slots (cnt atomics + NT colFixed scatter) | xh=fp16(x)
//                | Wp1 | Wp2   (block-range split, phases overlap)
//   3. agg256  : buf1h = fp16(Ahat @ xh)             (gather, f32 acc)
//   4. gemm1   : h1h   = fp16(relu(buf1h@W1+b1))     (MFMA, swapped operands)
//   5. gemm2   : buf2h = fp16((h1h@W2)*dinv[row])    (MFMA)
//   6. agg128  : out   = relu(di*(buf2h[i]+sum buf2h[src]) + b2)  f32
// ---------------------------------------------------------------------------

typedef _Float16 f16x8 __attribute__((ext_vector_type(8)));
typedef float f32x4 __attribute__((ext_vector_type(4)));

constexpr int CAP = 64;   // adjacency slots per node

// ---------------- prep: fill slots | pack_half | pack_w1 | pack_w2 ----------

__device__ inline void pack_w_body(const float* __restrict__ W, __half* __restrict__ Wp,
                                   int NC, int t) {
    const int NT = NC / 16;
    int lane = t & 63;
    int rest = t >> 6;
    int nt = rest % NT;
    int ks = rest / NT;
    int n = nt * 16 + (lane & 15);
    int k0 = ks * 32 + (lane >> 4) * 8;
    __half tmp[8];
#pragma unroll
    for (int j = 0; j < 8; ++j) tmp[j] = __float2half_rn(W[(size_t)(k0 + j) * NC + n]);
    ((uint4*)Wp)[t] = *(const uint4*)tmp;
}

__global__ __launch_bounds__(256) void prep_kernel(const int* __restrict__ src,
                                                   const int* __restrict__ dst, int E,
                                                   int* __restrict__ cnt,
                                                   int* __restrict__ colFixed,
                                                   const float* __restrict__ x,
                                                   __half* __restrict__ xh, int n8,
                                                   const float* __restrict__ W1,
                                                   __half* __restrict__ Wp1,
                                                   const float* __restrict__ W2,
                                                   __half* __restrict__ Wp2,
                                                   int nbFill, int nbPack) {
    const int b = blockIdx.x;
    const int tid = threadIdx.x;
    if (b < nbFill) {
        int e = b * 256 + tid;
        if (e < E) {
            int d = __builtin_nontemporal_load(dst + e);
            int s = __builtin_nontemporal_load(src + e);
            int slot = atomicAdd(&cnt[d], 1);
            // written once, re-read sparsely by aggregates -> keep out of L2
            if (slot < CAP)
                __builtin_nontemporal_store(s, &colFixed[(size_t)d * CAP + slot]);
        }
    } else if (b < nbFill + nbPack) {
        int i = (b - nbFill) * 256 + tid;
        if (i < n8) {
            float4 a = ((const float4*)x)[(size_t)i * 2];
            float4 bb = ((const float4*)x)[(size_t)i * 2 + 1];
            __half2 h[4];
            h[0] = __floats2half2_rn(a.x, a.y);
            h[1] = __floats2half2_rn(a.z, a.w);
            h[2] = __floats2half2_rn(bb.x, bb.y);
            h[3] = __floats2half2_rn(bb.z, bb.w);
            ((uint4*)xh)[i] = *(const uint4*)h;
        }
    } else if (b < nbFill + nbPack + 32) {
        int t = (b - nbFill - nbPack) * 256 + tid;        // < 8*16*64 = 8192
        pack_w_body(W1, Wp1, 256, t);
    } else {
        int t = (b - nbFill - nbPack - 32) * 256 + tid;   // < 8*8*64 = 4096
        pack_w_body(W2, Wp2, 128, t);
    }
}

// ---------------- aggregate F=256 (fp16 gather, f32 acc, fp16 out) ----------
// 4 waves/block, 1 dst row per wave. buf1h[i] = fp16(di*(di*xh[i] + sum w_s*xh[s]))
__global__ __launch_bounds__(256) void aggregate256_h(const __half* __restrict__ xh,
                                                      const int* __restrict__ cnt,
                                                      const int* __restrict__ colFixed,
                                                      __half* __restrict__ out, int N) {
    const int lane = threadIdx.x & 63;
    const int i = blockIdx.x * 4 + (threadIdx.x >> 6);
    if (i >= N) return;
    const int degt = cnt[i];
    const float di = rsqrtf((float)(degt + 1));
    const int deg = (degt < CAP) ? degt : CAP;
    const uint2* __restrict__ hv = (const uint2*)xh;  // 4 halves per slot
    uint2 raw = hv[(size_t)i * 64 + lane];
    float2 f0 = __half22float2(*(const __half2*)&raw.x);
    float2 f1 = __half22float2(*(const __half2*)&raw.y);
    float ax = di * f0.x, ay = di * f0.y, az = di * f1.x, aw = di * f1.y;
    const int* __restrict__ cl = colFixed + (size_t)i * CAP;
    int e = 0;
    for (; e + 8 <= deg; e += 8) {
        int s[8];
#pragma unroll
        for (int j = 0; j < 8; ++j) s[j] = cl[e + j];
        float w[8];
#pragma unroll
        for (int j = 0; j < 8; ++j) w[j] = rsqrtf((float)(cnt[s[j]] + 1));
        uint2 u[8];
#pragma unroll
        for (int j = 0; j < 8; ++j) u[j] = hv[(size_t)s[j] * 64 + lane];
#pragma unroll
        for (int j = 0; j < 8; ++j) {
            float2 g0 = __half22float2(*(const __half2*)&u[j].x);
            float2 g1 = __half22float2(*(const __half2*)&u[j].y);
            ax = fmaf(w[j], g0.x, ax);
            ay = fmaf(w[j], g0.y, ay);
            az = fmaf(w[j], g1.x, az);
            aw = fmaf(w[j], g1.y, aw);
        }
    }
    for (; e < deg; ++e) {
        int s = cl[e];
        float w = rsqrtf((float)(cnt[s] + 1));
        uint2 u = hv[(size_t)s * 64 + lane];
        float2 g0 = __half22float2(*(const __half2*)&u.x);
        float2 g1 = __half22float2(*(const __half2*)&u.y);
        ax = fmaf(w, g0.x, ax);
        ay = fmaf(w, g0.y, ay);
        az = fmaf(w, g1.x, az);
        aw = fmaf(w, g1.y, aw);
    }
    __half2 h0 = __floats2half2_rn(ax * di, ay * di);
    __half2 h1 = __floats2half2_rn(az * di, aw * di);
    uint2 o;
    o.x = *(const unsigned int*)&h0;
    o.y = *(const unsigned int*)&h1;
    ((uint2*)out)[(size_t)i * 64 + lane] = o;
}

// ---------------- GEMM1 (MFMA): h1h = fp16(relu(A@W1 + b1)), NC=256 ----------
// Swapped operands: D = mfma(Wfrag, Xfrag); lane owns 4 consecutive cols of
// one row -> packed 8B fp16 stores, no LDS.
__global__ __launch_bounds__(256) void gemm_mfma256(const __half* __restrict__ A,
                                                    const __half* __restrict__ Wp,
                                                    const float* __restrict__ bias,
                                                    __half* __restrict__ out, int M) {
    constexpr int NT = 16;
    const int lane = threadIdx.x & 63;
    const int wave = threadIdx.x >> 6;
    const int kg = lane >> 4;
    const int row = blockIdx.x * 64 + wave * 16 + (lane & 15);
    const int rowc = (row < M) ? row : (M - 1);

    f32x4 acc[NT];
#pragma unroll
    for (int nt = 0; nt < NT; ++nt) acc[nt] = {0.f, 0.f, 0.f, 0.f};

    const f16x8* __restrict__ Ap = (const f16x8*)(A + (size_t)rowc * 256 + kg * 8);
    const f16x8* __restrict__ Wf = (const f16x8*)Wp;

#pragma unroll
    for (int ks = 0; ks < 8; ++ks) {
        f16x8 xfrag = Ap[ks * 4];
        const f16x8* wrow = Wf + (size_t)(ks * NT) * 64 + lane;
#pragma unroll
        for (int nt = 0; nt < NT; ++nt) {
            f16x8 wfrag = wrow[nt * 64];
            acc[nt] = __builtin_amdgcn_mfma_f32_16x16x32_f16(wfrag, xfrag, acc[nt], 0, 0, 0);
        }
    }

    if (row < M) {
#pragma unroll
        for (int nt = 0; nt < NT; ++nt) {
            const int n0 = nt * 16 + kg * 4;
            f32x4 v = acc[nt];
            float4 bb = *(const float4*)(bias + n0);
            v[0] = fmaxf(v[0] + bb.x, 0.f);
            v[1] = fmaxf(v[1] + bb.y, 0.f);
            v[2] = fmaxf(v[2] + bb.z, 0.f);
            v[3] = fmaxf(v[3] + bb.w, 0.f);
            __half2 h0 = __floats2half2_rn(v[0], v[1]);
            __half2 h1 = __floats2half2_rn(v[2], v[3]);
            uint2 o;
            o.x = *(const unsigned int*)&h0;
            o.y = *(const unsigned int*)&h1;
            *(uint2*)(out + (size_t)row * 256 + n0) = o;
        }
    }
}

// ---------------- GEMM2 (MFMA): buf2h = fp16((A@W2) * rsqrt(cnt[row]+1)) ----
__global__ __launch_bounds__(256) void gemm_mfma128(const __half* __restrict__ A,
                                                    const __half* __restrict__ Wp,
                                                    const int* __restrict__ cnt,
                                                    __half* __restrict__ out, int M) {
    constexpr int NT = 8;
    const int lane = threadIdx.x & 63;
    const int wave = threadIdx.x >> 6;
    const int kg = lane >> 4;
    const int row = blockIdx.x * 64 + wave * 16 + (lane & 15);
    const int rowc = (row < M) ? row : (M - 1);

    f32x4 acc[NT];
#pragma unroll
    for (int nt = 0; nt < NT; ++nt) acc[nt] = {0.f, 0.f, 0.f, 0.f};

    const f16x8* __restrict__ Ap = (const f16x8*)(A + (size_t)rowc * 256 + kg * 8);
    const f16x8* __restrict__ Wf = (const f16x8*)Wp;

#pragma unroll
    for (int ks = 0; ks < 8; ++ks) {
        f16x8 xfrag = Ap[ks * 4];
        const f16x8* wrow = Wf + (size_t)(ks * NT) * 64 + lane;
#pragma unroll
        for (int nt = 0; nt < NT; ++nt) {
            f16x8 wfrag = wrow[nt * 64];
            acc[nt] = __builtin_amdgcn_mfma_f32_16x16x32_f16(wfrag, xfrag, acc[nt], 0, 0, 0);
        }
    }

    if (row < M) {
        float rs = rsqrtf((float)(cnt[row] + 1));
#pragma unroll
        for (int nt = 0; nt < NT; ++nt) {
            const int n0 = nt * 16 + kg * 4;
            f32x4 v = acc[nt];
            __half2 h0 = __floats2half2_rn(v[0] * rs, v[1] * rs);
            __half2 h1 = __floats2half2_rn(v[2] * rs, v[3] * rs);
            uint2 o;
            o.x = *(const unsigned int*)&h0;
            o.y = *(const unsigned int*)&h1;
            *(uint2*)(out + (size_t)row * 128 + n0) = o;
        }
    }
}

// ---------------- final aggregate F=128 ----------------
// h pre-scaled by dinv[src]; out[i] = relu(di*(h[i]+sum h[src]) + b), f32.
// 4 waves/block, 1 row per wave.
__global__ __launch_bounds__(256) void aggregate128_h_bias_relu(const __half* __restrict__ h,
                                                                const int* __restrict__ cnt,
                                                                const int* __restrict__ colFixed,
                                                                const float* __restrict__ bias,
                                                                float* __restrict__ out, int N) {
    const int lane = threadIdx.x & 63;
    const int i = blockIdx.x * 4 + (threadIdx.x >> 6);
    if (i >= N) return;
    const int degt = cnt[i];
    const float di = rsqrtf((float)(degt + 1));
    const int deg = (degt < CAP) ? degt : CAP;
    const unsigned int* __restrict__ hv = (const unsigned int*)h;  // half2 per slot
    float2 v = __half22float2(*(const __half2*)&hv[(size_t)i * 64 + lane]);
    float ax = v.x, ay = v.y;
    const int* __restrict__ cl = colFixed + (size_t)i * CAP;
    int e = 0;
    for (; e + 8 <= deg; e += 8) {
        int s[8];
#pragma unroll
        for (int j = 0; j < 8; ++j) s[j] = cl[e + j];
        unsigned int u[8];
#pragma unroll
        for (int j = 0; j < 8; ++j) u[j] = hv[(size_t)s[j] * 64 + lane];
#pragma unroll
        for (int j = 0; j < 8; ++j) {
            float2 g = __half22float2(*(const __half2*)&u[j]);
            ax += g.x;
            ay += g.y;
        }
    }
    for (; e < deg; ++e) {
        float2 g = __half22float2(*(const __half2*)&hv[(size_t)cl[e] * 64 + lane]);
        ax += g.x;
        ay += g.y;
    }
    float2 bb = ((const float2*)bias)[lane];
    float2 r;
    r.x = fmaxf(fmaf(ax, di, bb.x), 0.f);
    r.y = fmaxf(fmaf(ay, di, bb.y), 0.f);
    ((float2*)out)[(size_t)i * 64 + lane] = r;
}

extern "C" void kernel_launch(void* const* d_in, const int* in_sizes, int n_in,
                              void* d_out, int out_size, void* d_ws, size_t ws_size,
                              hipStream_t stream) {
    const float* x  = (const float*)d_in[0];
    const int*   ei = (const int*)d_in[1];
    const float* W1 = (const float*)d_in[2];
    const float* b1 = (const float*)d_in[3];
    const float* W2 = (const float*)d_in[4];
    const float* b2 = (const float*)d_in[5];
    float* out = (float*)d_out;

    const int N = in_sizes[0] / 256;
    const int E = in_sizes[1] / 2;
    const int* src = ei;
    const int* dst = ei + E;

    char* ws = (char*)d_ws;
    size_t off = 0;
    auto alloc = [&](size_t bytes) -> char* {
        char* p = ws + off;
        off += (bytes + 255) & ~(size_t)255;
        return p;
    };
    int*    cnt      = (int*)alloc((size_t)N * 4);
    int*    colFixed = (int*)alloc((size_t)N * CAP * 4);
    __half* Wp1      = (__half*)alloc((size_t)256 * 256 * 2);
    __half* Wp2      = (__half*)alloc((size_t)256 * 128 * 2);
    // bufA: xh (gather source, dead after agg256), then h1h (GEMM1 out)
    // bufB: buf1h (agg256 out, dead after GEMM1), then buf2h (GEMM2 out)
    __half* bufA     = (__half*)alloc((size_t)N * 256 * 2);
    __half* bufB     = (__half*)alloc((size_t)N * 256 * 2);
    __half* xh    = bufA;
    __half* h1h   = bufA;
    __half* buf1h = bufB;
    __half* buf2h = bufB;

    hipMemsetAsync(cnt, 0, (size_t)N * 4, stream);

    // prep: fill adjacency slots | pack xh | pack Wp1 | pack Wp2
    const int n8 = (N * 256) / 8;
    const int nbFill = (E + 255) / 256;
    const int nbPack = (n8 + 255) / 256;
    const int nbPrep = nbFill + nbPack + 32 + 16;
    prep_kernel<<<nbPrep, 256, 0, stream>>>(src, dst, E, cnt, colFixed, x, xh, n8,
                                            W1, Wp1, W2, Wp2, nbFill, nbPack);

    const int AB = (N + 3) / 4;     // 4 rows per block
    const int GB = (N + 63) / 64;   // 64 rows per block

    aggregate256_h<<<AB, 256, 0, stream>>>(xh, cnt, colFixed, buf1h, N);
    gemm_mfma256<<<GB, 256, 0, stream>>>(buf1h, Wp1, b1, h1h, N);
    gemm_mfma128<<<GB, 256, 0, stream>>>(h1h, Wp2, cnt, buf2h, N);
    aggregate128_h_bias_relu<<<AB, 256, 0, stream>>>(buf2h, cnt, colFixed, b2, out, N);
}

// Round 9
// 454.273 us; speedup vs baseline: 1.0588x; 1.0588x over previous
//
#include <hip/hip_runtime.h>
#include <hip/hip_fp16.h>

// ---------------------------------------------------------------------------
// 2-layer GCN encoder (PyG GCNConv semantics). fp16 storage + MFMA GEMMs,
// f32 accumulation. Fixed-capacity adjacency slots (CAP=64, deg~Poisson(16),
// overflow prob ~1e-20, clamped). dinv = rsqrtf(cnt+1) inline everywhere.
// Pipeline (1 memset + 4 kernels):
//   1. memset cnt=0
//   2. prep    : fill slots (cnt atomics + colFixed scatter) | xh=fp16(x)
//                | Wp1 | Wp2   (block-range split, phases overlap)
//   3. agg256  : buf1h = fp16(Ahat @ xh)             (gather, f32 acc)
//   4. gemm12  : phase1 h1=relu(buf1h@W1+b1) -> per-wave LDS strip (fp16),
//                phase2 buf2h = fp16((h1@W2)*dinv[row])   (fused MFMA, no
//                cross-wave traffic, no barrier)
//   5. agg128  : out = relu(di*(buf2h[i]+sum buf2h[src]) + b2)  f32
// ---------------------------------------------------------------------------

typedef _Float16 f16x8 __attribute__((ext_vector_type(8)));
typedef float f32x4 __attribute__((ext_vector_type(4)));

constexpr int CAP = 64;   // adjacency slots per node

// ---------------- prep: fill slots | pack_half | pack_w1 | pack_w2 ----------

__device__ inline void pack_w_body(const float* __restrict__ W, __half* __restrict__ Wp,
                                   int NC, int t) {
    const int NT = NC / 16;
    int lane = t & 63;
    int rest = t >> 6;
    int nt = rest % NT;
    int ks = rest / NT;
    int n = nt * 16 + (lane & 15);
    int k0 = ks * 32 + (lane >> 4) * 8;
    __half tmp[8];
#pragma unroll
    for (int j = 0; j < 8; ++j) tmp[j] = __float2half_rn(W[(size_t)(k0 + j) * NC + n]);
    ((uint4*)Wp)[t] = *(const uint4*)tmp;
}

__global__ __launch_bounds__(256) void prep_kernel(const int* __restrict__ src,
                                                   const int* __restrict__ dst, int E,
                                                   int* __restrict__ cnt,
                                                   int* __restrict__ colFixed,
                                                   const float* __restrict__ x,
                                                   __half* __restrict__ xh, int n8,
                                                   const float* __restrict__ W1,
                                                   __half* __restrict__ Wp1,
                                                   const float* __restrict__ W2,
                                                   __half* __restrict__ Wp2,
                                                   int nbFill, int nbPack) {
    const int b = blockIdx.x;
    const int tid = threadIdx.x;
    if (b < nbFill) {
        int e = b * 256 + tid;
        if (e < E) {
            int d = dst[e];
            int slot = atomicAdd(&cnt[d], 1);
            if (slot < CAP) colFixed[(size_t)d * CAP + slot] = src[e];
        }
    } else if (b < nbFill + nbPack) {
        int i = (b - nbFill) * 256 + tid;
        if (i < n8) {
            float4 a = ((const float4*)x)[(size_t)i * 2];
            float4 bb = ((const float4*)x)[(size_t)i * 2 + 1];
            __half2 h[4];
            h[0] = __floats2half2_rn(a.x, a.y);
            h[1] = __floats2half2_rn(a.z, a.w);
            h[2] = __floats2half2_rn(bb.x, bb.y);
            h[3] = __floats2half2_rn(bb.z, bb.w);
            ((uint4*)xh)[i] = *(const uint4*)h;
        }
    } else if (b < nbFill + nbPack + 32) {
        int t = (b - nbFill - nbPack) * 256 + tid;        // < 8*16*64 = 8192
        pack_w_body(W1, Wp1, 256, t);
    } else {
        int t = (b - nbFill - nbPack - 32) * 256 + tid;   // < 8*8*64 = 4096
        pack_w_body(W2, Wp2, 128, t);
    }
}

// ---------------- aggregate F=256 (fp16 gather, f32 acc, fp16 out) ----------
// 4 waves/block, 1 dst row per wave. buf1h[i] = fp16(di*(di*xh[i] + sum w_s*xh[s]))
__global__ __launch_bounds__(256) void aggregate256_h(const __half* __restrict__ xh,
                                                      const int* __restrict__ cnt,
                                                      const int* __restrict__ colFixed,
                                                      __half* __restrict__ out, int N) {
    const int lane = threadIdx.x & 63;
    const int i = blockIdx.x * 4 + (threadIdx.x >> 6);
    if (i >= N) return;
    const int degt = cnt[i];
    const float di = rsqrtf((float)(degt + 1));
    const int deg = (degt < CAP) ? degt : CAP;
    const uint2* __restrict__ hv = (const uint2*)xh;  // 4 halves per slot
    uint2 raw = hv[(size_t)i * 64 + lane];
    float2 f0 = __half22float2(*(const __half2*)&raw.x);
    float2 f1 = __half22float2(*(const __half2*)&raw.y);
    float ax = di * f0.x, ay = di * f0.y, az = di * f1.x, aw = di * f1.y;
    const int* __restrict__ cl = colFixed + (size_t)i * CAP;
    int e = 0;
    for (; e + 8 <= deg; e += 8) {
        int s[8];
#pragma unroll
        for (int j = 0; j < 8; ++j) s[j] = cl[e + j];
        float w[8];
#pragma unroll
        for (int j = 0; j < 8; ++j) w[j] = rsqrtf((float)(cnt[s[j]] + 1));
        uint2 u[8];
#pragma unroll
        for (int j = 0; j < 8; ++j) u[j] = hv[(size_t)s[j] * 64 + lane];
#pragma unroll
        for (int j = 0; j < 8; ++j) {
            float2 g0 = __half22float2(*(const __half2*)&u[j].x);
            float2 g1 = __half22float2(*(const __half2*)&u[j].y);
            ax = fmaf(w[j], g0.x, ax);
            ay = fmaf(w[j], g0.y, ay);
            az = fmaf(w[j], g1.x, az);
            aw = fmaf(w[j], g1.y, aw);
        }
    }
    for (; e < deg; ++e) {
        int s = cl[e];
        float w = rsqrtf((float)(cnt[s] + 1));
        uint2 u = hv[(size_t)s * 64 + lane];
        float2 g0 = __half22float2(*(const __half2*)&u.x);
        float2 g1 = __half22float2(*(const __half2*)&u.y);
        ax = fmaf(w, g0.x, ax);
        ay = fmaf(w, g0.y, ay);
        az = fmaf(w, g1.x, az);
        aw = fmaf(w, g1.y, aw);
    }
    __half2 h0 = __floats2half2_rn(ax * di, ay * di);
    __half2 h1 = __floats2half2_rn(az * di, aw * di);
    uint2 o;
    o.x = *(const unsigned int*)&h0;
    o.y = *(const unsigned int*)&h1;
    ((uint2*)out)[(size_t)i * 64 + lane] = o;
}

// ---------------- fused GEMM1+GEMM2 via per-wave LDS strip ----------------
// Block = 256 thr = 4 waves; wave w owns rows blockIdx.x*64 + w*16 .. +15.
// Phase 1 (== gemm_mfma256): acc1 = A@W1 swapped-operand MFMA; lane l
//   (kg=l>>4, r=l&15) holds h1[row][nt*16+kg*4+0..3]. relu(+b1), fp16-pack,
//   store to private LDS strip hs[w][r][col] (PITCH=264 -> b128 reads spread
//   evenly across banks). acc1 dies here; no barrier (wave-private strip).
// Phase 2 (== gemm_mfma128): A-frag = hs[w][r][ks*32+kg*8 .. +7] (ds_read_b128),
//   acc2 = h1@W2; epilogue * rsqrt(cnt[row]+1), fp16 store.
__global__ __launch_bounds__(256) void gemm12_lds(const __half* __restrict__ A,
                                                  const __half* __restrict__ Wp1,
                                                  const float* __restrict__ bias1,
                                                  const __half* __restrict__ Wp2,
                                                  const int* __restrict__ cnt,
                                                  __half* __restrict__ out, int M) {
    constexpr int PITCH = 264;   // halves; 528B row stride
    __shared__ _Float16 hs[4][16][PITCH];

    const int lane = threadIdx.x & 63;
    const int wave = threadIdx.x >> 6;
    const int kg = lane >> 4;
    const int r = lane & 15;
    const int row = blockIdx.x * 64 + wave * 16 + r;
    const int rowc = (row < M) ? row : (M - 1);

    // -------- Phase 1: h1 = relu(A @ W1 + b1) --------
    f32x4 acc1[16];
#pragma unroll
    for (int nt = 0; nt < 16; ++nt) acc1[nt] = {0.f, 0.f, 0.f, 0.f};

    const f16x8* __restrict__ Ap = (const f16x8*)(A + (size_t)rowc * 256 + kg * 8);
    const f16x8* __restrict__ Wf1 = (const f16x8*)Wp1;
#pragma unroll
    for (int ks = 0; ks < 8; ++ks) {
        f16x8 xfrag = Ap[ks * 4];
        const f16x8* wrow = Wf1 + (size_t)(ks * 16) * 64 + lane;
#pragma unroll
        for (int nt = 0; nt < 16; ++nt) {
            f16x8 wfrag = wrow[nt * 64];
            acc1[nt] = __builtin_amdgcn_mfma_f32_16x16x32_f16(wfrag, xfrag, acc1[nt], 0, 0, 0);
        }
    }

#pragma unroll
    for (int nt = 0; nt < 16; ++nt) {
        float4 bb = *(const float4*)(bias1 + nt * 16 + kg * 4);
        f32x4 v = acc1[nt];
        v[0] = fmaxf(v[0] + bb.x, 0.f);
        v[1] = fmaxf(v[1] + bb.y, 0.f);
        v[2] = fmaxf(v[2] + bb.z, 0.f);
        v[3] = fmaxf(v[3] + bb.w, 0.f);
        __half2 h0 = __floats2half2_rn(v[0], v[1]);
        __half2 h1 = __floats2half2_rn(v[2], v[3]);
        uint2 o;
        o.x = *(const unsigned int*)&h0;
        o.y = *(const unsigned int*)&h1;
        *(uint2*)&hs[wave][r][nt * 16 + kg * 4] = o;
    }
    // no __syncthreads: strip is wave-private; compiler inserts lgkmcnt waits.

    // -------- Phase 2: buf2 = (h1 @ W2) * dinv[row] --------
    f32x4 acc2[8];
#pragma unroll
    for (int nt = 0; nt < 8; ++nt) acc2[nt] = {0.f, 0.f, 0.f, 0.f};

    const f16x8* __restrict__ Wf2 = (const f16x8*)Wp2;
#pragma unroll
    for (int ks = 0; ks < 8; ++ks) {
        f16x8 xfrag = *(const f16x8*)&hs[wave][r][ks * 32 + kg * 8];
        const f16x8* wrow = Wf2 + (size_t)(ks * 8) * 64 + lane;
#pragma unroll
        for (int nt = 0; nt < 8; ++nt) {
            f16x8 wfrag = wrow[nt * 64];
            acc2[nt] = __builtin_amdgcn_mfma_f32_16x16x32_f16(wfrag, xfrag, acc2[nt], 0, 0, 0);
        }
    }

    if (row < M) {
        float rs = rsqrtf((float)(cnt[row] + 1));
#pragma unroll
        for (int nt = 0; nt < 8; ++nt) {
            const int n0 = nt * 16 + kg * 4;
            f32x4 v = acc2[nt];
            __half2 h0 = __floats2half2_rn(v[0] * rs, v[1] * rs);
            __half2 h1 = __floats2half2_rn(v[2] * rs, v[3] * rs);
            uint2 o;
            o.x = *(const unsigned int*)&h0;
            o.y = *(const unsigned int*)&h1;
            *(uint2*)(out + (size_t)row * 128 + n0) = o;
        }
    }
}

// ---------------- final aggregate F=128 ----------------
// h pre-scaled by dinv[src]; out[i] = relu(di*(h[i]+sum h[src]) + b), f32.
// 4 waves/block, 1 row per wave.
__global__ __launch_bounds__(256) void aggregate128_h_bias_relu(const __half* __restrict__ h,
                                                                const int* __restrict__ cnt,
                                                                const int* __restrict__ colFixed,
                                                                const float* __restrict__ bias,
                                                                float* __restrict__ out, int N) {
    const int lane = threadIdx.x & 63;
    const int i = blockIdx.x * 4 + (threadIdx.x >> 6);
    if (i >= N) return;
    const int degt = cnt[i];
    const float di = rsqrtf((float)(degt + 1));
    const int deg = (degt < CAP) ? degt : CAP;
    const unsigned int* __restrict__ hv = (const unsigned int*)h;  // half2 per slot
    float2 v = __half22float2(*(const __half2*)&hv[(size_t)i * 64 + lane]);
    float ax = v.x, ay = v.y;
    const int* __restrict__ cl = colFixed + (size_t)i * CAP;
    int e = 0;
    for (; e + 8 <= deg; e += 8) {
        int s[8];
#pragma unroll
        for (int j = 0; j < 8; ++j) s[j] = cl[e + j];
        unsigned int u[8];
#pragma unroll
        for (int j = 0; j < 8; ++j) u[j] = hv[(size_t)s[j] * 64 + lane];
#pragma unroll
        for (int j = 0; j < 8; ++j) {
            float2 g = __half22float2(*(const __half2*)&u[j]);
            ax += g.x;
            ay += g.y;
        }
    }
    for (; e < deg; ++e) {
        float2 g = __half22float2(*(const __half2*)&hv[(size_t)cl[e] * 64 + lane]);
        ax += g.x;
        ay += g.y;
    }
    float2 bb = ((const float2*)bias)[lane];
    float2 r;
    r.x = fmaxf(fmaf(ax, di, bb.x), 0.f);
    r.y = fmaxf(fmaf(ay, di, bb.y), 0.f);
    ((float2*)out)[(size_t)i * 64 + lane] = r;
}

extern "C" void kernel_launch(void* const* d_in, const int* in_sizes, int n_in,
                              void* d_out, int out_size, void* d_ws, size_t ws_size,
                              hipStream_t stream) {
    const float* x  = (const float*)d_in[0];
    const int*   ei = (const int*)d_in[1];
    const float* W1 = (const float*)d_in[2];
    const float* b1 = (const float*)d_in[3];
    const float* W2 = (const float*)d_in[4];
    const float* b2 = (const float*)d_in[5];
    float* out = (float*)d_out;

    const int N = in_sizes[0] / 256;
    const int E = in_sizes[1] / 2;
    const int* src = ei;
    const int* dst = ei + E;

    char* ws = (char*)d_ws;
    size_t off = 0;
    auto alloc = [&](size_t bytes) -> char* {
        char* p = ws + off;
        off += (bytes + 255) & ~(size_t)255;
        return p;
    };
    int*    cnt      = (int*)alloc((size_t)N * 4);
    int*    colFixed = (int*)alloc((size_t)N * CAP * 4);
    __half* Wp1      = (__half*)alloc((size_t)256 * 256 * 2);
    __half* Wp2      = (__half*)alloc((size_t)256 * 128 * 2);
    // bufA: xh (gather source, dead after agg256), then buf2h (gemm12 out)
    // bufB: buf1h (agg256 out, read by gemm12)
    __half* bufA     = (__half*)alloc((size_t)N * 256 * 2);
    __half* bufB     = (__half*)alloc((size_t)N * 256 * 2);
    __half* xh    = bufA;
    __half* buf2h = bufA;
    __half* buf1h = bufB;

    hipMemsetAsync(cnt, 0, (size_t)N * 4, stream);

    // prep: fill adjacency slots | pack xh | pack Wp1 | pack Wp2
    const int n8 = (N * 256) / 8;
    const int nbFill = (E + 255) / 256;
    const int nbPack = (n8 + 255) / 256;
    const int nbPrep = nbFill + nbPack + 32 + 16;
    prep_kernel<<<nbPrep, 256, 0, stream>>>(src, dst, E, cnt, colFixed, x, xh, n8,
                                            W1, Wp1, W2, Wp2, nbFill, nbPack);

    const int AB = (N + 3) / 4;     // 4 rows per block
    const int GB = (N + 63) / 64;   // 64 rows per block

    aggregate256_h<<<AB, 256, 0, stream>>>(xh, cnt, colFixed, buf1h, N);
    gemm12_lds<<<GB, 256, 0, stream>>>(buf1h, Wp1, b1, Wp2, cnt, buf2h, N);
    aggregate128_h_bias_relu<<<AB, 256, 0, stream>>>(buf2h, cnt, colFixed, b2, out, N);
}

// Round 11
// 416.036 us; speedup vs baseline: 1.1561x; 1.0919x over previous
//
#include <hip/hip_runtime.h>
#include <hip/hip_fp16.h>

// ---------------------------------------------------------------------------
// 2-layer GCN encoder (PyG GCNConv semantics). fp16 storage + MFMA GEMMs,
// f32 accumulation. Fixed-capacity adjacency slots (CAP=64, deg~Poisson(16),
// overflow prob ~1e-20, clamped). dinv = rsqrtf(cnt+1) inline everywhere.
// Fill is XCD-partitioned: block b handles edge chunk b>>3, selector b&7 ==
// dst&7, so each XCD's colFixed slice (3.2 MB) stays L2-resident.
// Pipeline (1 memset + 4 kernels):
//   1. memset cnt=0
//   2. prep    : XCD-partitioned fill | xh=fp16(x) | Wp1 | Wp2
//   3. agg256  : buf1h = fp16(Ahat @ xh)            (gather, f32 acc)
//   4. gemm12  : h1=relu(buf1h@W1+b1) -> per-wave LDS strip (fp16), then
//                buf2h = fp16((h1@W2)*dinv[row])    (fused MFMA, no barrier)
//   5. agg128  : out = relu(di*(buf2h[i]+sum buf2h[src]) + b2)  f32
// ---------------------------------------------------------------------------

typedef _Float16 f16x8 __attribute__((ext_vector_type(8)));
typedef float f32x4 __attribute__((ext_vector_type(4)));
typedef int i32x4 __attribute__((ext_vector_type(4)));      // NT-load friendly
typedef float fv4 __attribute__((ext_vector_type(4)));      // NT-load friendly

constexpr int CAP = 64;           // adjacency slots per node
constexpr int FILL_CHUNK = 2048;  // edges per chunk (256 thr * 8)

// ---------------- prep: XCD-fill | pack_half | pack_w1 | pack_w2 ----------

__device__ inline void pack_w_body(const float* __restrict__ W, __half* __restrict__ Wp,
                                   int NC, int t) {
    const int NT = NC / 16;
    int lane = t & 63;
    int rest = t >> 6;
    int nt = rest % NT;
    int ks = rest / NT;
    int n = nt * 16 + (lane & 15);
    int k0 = ks * 32 + (lane >> 4) * 8;
    __half tmp[8];
#pragma unroll
    for (int j = 0; j < 8; ++j) tmp[j] = __float2half_rn(W[(size_t)(k0 + j) * NC + n]);
    ((uint4*)Wp)[t] = *(const uint4*)tmp;
}

__global__ __launch_bounds__(256) void prep_kernel(const int* __restrict__ src,
                                                   const int* __restrict__ dst, int E,
                                                   int* __restrict__ cnt,
                                                   int* __restrict__ colFixed,
                                                   const float* __restrict__ x,
                                                   __half* __restrict__ xh, int n8,
                                                   const float* __restrict__ W1,
                                                   __half* __restrict__ Wp1,
                                                   const float* __restrict__ W2,
                                                   __half* __restrict__ Wp2,
                                                   int nbFill, int nbPack) {
    const int b = blockIdx.x;
    const int tid = threadIdx.x;
    if (b < nbFill) {
        // XCD-partitioned fill: selector = b&7 (round-robin blockIdx->XCD),
        // chunk = b>>3. Only edges with dst&7 == selector are handled here,
        // keeping this XCD's colFixed slice (~3.2 MB) L2-resident.
        const int sel = b & 7;
        const int chunk = b >> 3;
        const int e0 = chunk * FILL_CHUNK + tid * 8;
        if (e0 + 8 <= E) {
            i32x4 da = __builtin_nontemporal_load((const i32x4*)(dst + e0));
            i32x4 db = __builtin_nontemporal_load((const i32x4*)(dst + e0) + 1);
            i32x4 sa = __builtin_nontemporal_load((const i32x4*)(src + e0));
            i32x4 sb = __builtin_nontemporal_load((const i32x4*)(src + e0) + 1);
            int d[8] = {da[0], da[1], da[2], da[3], db[0], db[1], db[2], db[3]};
            int s[8] = {sa[0], sa[1], sa[2], sa[3], sb[0], sb[1], sb[2], sb[3]};
#pragma unroll
            for (int j = 0; j < 8; ++j) {
                if ((d[j] & 7) == sel) {
                    int slot = atomicAdd(&cnt[d[j]], 1);
                    if (slot < CAP) colFixed[(size_t)d[j] * CAP + slot] = s[j];
                }
            }
        } else {
            for (int j = 0; j < 8; ++j) {
                int e = e0 + j;
                if (e < E) {
                    int dd = dst[e];
                    if ((dd & 7) == sel) {
                        int slot = atomicAdd(&cnt[dd], 1);
                        if (slot < CAP) colFixed[(size_t)dd * CAP + slot] = src[e];
                    }
                }
            }
        }
    } else if (b < nbFill + nbPack) {
        int i = (b - nbFill) * 256 + tid;
        if (i < n8) {
            // NT loads: x is streamed once; don't evict colFixed slices.
            fv4 a = __builtin_nontemporal_load((const fv4*)x + (size_t)i * 2);
            fv4 bb = __builtin_nontemporal_load((const fv4*)x + (size_t)i * 2 + 1);
            __half2 h[4];
            h[0] = __floats2half2_rn(a[0], a[1]);
            h[1] = __floats2half2_rn(a[2], a[3]);
            h[2] = __floats2half2_rn(bb[0], bb[1]);
            h[3] = __floats2half2_rn(bb[2], bb[3]);
            ((uint4*)xh)[i] = *(const uint4*)h;
        }
    } else if (b < nbFill + nbPack + 32) {
        int t = (b - nbFill - nbPack) * 256 + tid;        // < 8*16*64 = 8192
        pack_w_body(W1, Wp1, 256, t);
    } else {
        int t = (b - nbFill - nbPack - 32) * 256 + tid;   // < 8*8*64 = 4096
        pack_w_body(W2, Wp2, 128, t);
    }
}

// ---------------- aggregate F=256 (fp16 gather, f32 acc, fp16 out) ----------
// 4 waves/block, 1 dst row per wave. buf1h[i] = fp16(di*(di*xh[i] + sum w_s*xh[s]))
__global__ __launch_bounds__(256) void aggregate256_h(const __half* __restrict__ xh,
                                                      const int* __restrict__ cnt,
                                                      const int* __restrict__ colFixed,
                                                      __half* __restrict__ out, int N) {
    const int lane = threadIdx.x & 63;
    const int i = blockIdx.x * 4 + (threadIdx.x >> 6);
    if (i >= N) return;
    const int degt = cnt[i];
    const float di = rsqrtf((float)(degt + 1));
    const int deg = (degt < CAP) ? degt : CAP;
    const uint2* __restrict__ hv = (const uint2*)xh;  // 4 halves per slot
    uint2 raw = hv[(size_t)i * 64 + lane];
    float2 f0 = __half22float2(*(const __half2*)&raw.x);
    float2 f1 = __half22float2(*(const __half2*)&raw.y);
    float ax = di * f0.x, ay = di * f0.y, az = di * f1.x, aw = di * f1.y;
    const int* __restrict__ cl = colFixed + (size_t)i * CAP;
    int e = 0;
    for (; e + 8 <= deg; e += 8) {
        int s[8];
#pragma unroll
        for (int j = 0; j < 8; ++j) s[j] = cl[e + j];
        float w[8];
#pragma unroll
        for (int j = 0; j < 8; ++j) w[j] = rsqrtf((float)(cnt[s[j]] + 1));
        uint2 u[8];
#pragma unroll
        for (int j = 0; j < 8; ++j) u[j] = hv[(size_t)s[j] * 64 + lane];
#pragma unroll
        for (int j = 0; j < 8; ++j) {
            float2 g0 = __half22float2(*(const __half2*)&u[j].x);
            float2 g1 = __half22float2(*(const __half2*)&u[j].y);
            ax = fmaf(w[j], g0.x, ax);
            ay = fmaf(w[j], g0.y, ay);
            az = fmaf(w[j], g1.x, az);
            aw = fmaf(w[j], g1.y, aw);
        }
    }
    for (; e < deg; ++e) {
        int s = cl[e];
        float w = rsqrtf((float)(cnt[s] + 1));
        uint2 u = hv[(size_t)s * 64 + lane];
        float2 g0 = __half22float2(*(const __half2*)&u.x);
        float2 g1 = __half22float2(*(const __half2*)&u.y);
        ax = fmaf(w, g0.x, ax);
        ay = fmaf(w, g0.y, ay);
        az = fmaf(w, g1.x, az);
        aw = fmaf(w, g1.y, aw);
    }
    __half2 h0 = __floats2half2_rn(ax * di, ay * di);
    __half2 h1 = __floats2half2_rn(az * di, aw * di);
    uint2 o;
    o.x = *(const unsigned int*)&h0;
    o.y = *(const unsigned int*)&h1;
    ((uint2*)out)[(size_t)i * 64 + lane] = o;
}

// ---------------- fused GEMM1+GEMM2 via per-wave LDS strip ----------------
// Block = 256 thr = 4 waves; wave w owns rows blockIdx.x*64 + w*16 .. +15.
// Phase 1: acc1 = A@W1 swapped-operand MFMA; relu(+b1), fp16-pack into
//   wave-private LDS strip (PITCH=264 -> b128 reads spread across banks).
// Phase 2: A-frag = hs[w][r][ks*32+kg*8..+7]; acc2 = h1@W2; * rsqrt(cnt+1).
__global__ __launch_bounds__(256) void gemm12_lds(const __half* __restrict__ A,
                                                  const __half* __restrict__ Wp1,
                                                  const float* __restrict__ bias1,
                                                  const __half* __restrict__ Wp2,
                                                  const int* __restrict__ cnt,
                                                  __half* __restrict__ out, int M) {
    constexpr int PITCH = 264;   // halves; 528B row stride
    __shared__ _Float16 hs[4][16][PITCH];

    const int lane = threadIdx.x & 63;
    const int wave = threadIdx.x >> 6;
    const int kg = lane >> 4;
    const int r = lane & 15;
    const int row = blockIdx.x * 64 + wave * 16 + r;
    const int rowc = (row < M) ? row : (M - 1);

    // -------- Phase 1: h1 = relu(A @ W1 + b1) --------
    f32x4 acc1[16];
#pragma unroll
    for (int nt = 0; nt < 16; ++nt) acc1[nt] = {0.f, 0.f, 0.f, 0.f};

    const f16x8* __restrict__ Ap = (const f16x8*)(A + (size_t)rowc * 256 + kg * 8);
    const f16x8* __restrict__ Wf1 = (const f16x8*)Wp1;
#pragma unroll
    for (int ks = 0; ks < 8; ++ks) {
        f16x8 xfrag = Ap[ks * 4];
        const f16x8* wrow = Wf1 + (size_t)(ks * 16) * 64 + lane;
#pragma unroll
        for (int nt = 0; nt < 16; ++nt) {
            f16x8 wfrag = wrow[nt * 64];
            acc1[nt] = __builtin_amdgcn_mfma_f32_16x16x32_f16(wfrag, xfrag, acc1[nt], 0, 0, 0);
        }
    }

#pragma unroll
    for (int nt = 0; nt < 16; ++nt) {
        float4 bb = *(const float4*)(bias1 + nt * 16 + kg * 4);
        f32x4 v = acc1[nt];
        v[0] = fmaxf(v[0] + bb.x, 0.f);
        v[1] = fmaxf(v[1] + bb.y, 0.f);
        v[2] = fmaxf(v[2] + bb.z, 0.f);
        v[3] = fmaxf(v[3] + bb.w, 0.f);
        __half2 h0 = __floats2half2_rn(v[0], v[1]);
        __half2 h1 = __floats2half2_rn(v[2], v[3]);
        uint2 o;
        o.x = *(const unsigned int*)&h0;
        o.y = *(const unsigned int*)&h1;
        *(uint2*)&hs[wave][r][nt * 16 + kg * 4] = o;
    }
    // no __syncthreads: strip is wave-private; compiler inserts lgkmcnt waits.

    // -------- Phase 2: buf2 = (h1 @ W2) * dinv[row] --------
    f32x4 acc2[8];
#pragma unroll
    for (int nt = 0; nt < 8; ++nt) acc2[nt] = {0.f, 0.f, 0.f, 0.f};

    const f16x8* __restrict__ Wf2 = (const f16x8*)Wp2;
#pragma unroll
    for (int ks = 0; ks < 8; ++ks) {
        f16x8 xfrag = *(const f16x8*)&hs[wave][r][ks * 32 + kg * 8];
        const f16x8* wrow = Wf2 + (size_t)(ks * 8) * 64 + lane;
#pragma unroll
        for (int nt = 0; nt < 8; ++nt) {
            f16x8 wfrag = wrow[nt * 64];
            acc2[nt] = __builtin_amdgcn_mfma_f32_16x16x32_f16(wfrag, xfrag, acc2[nt], 0, 0, 0);
        }
    }

    if (row < M) {
        float rs = rsqrtf((float)(cnt[row] + 1));
#pragma unroll
        for (int nt = 0; nt < 8; ++nt) {
            const int n0 = nt * 16 + kg * 4;
            f32x4 v = acc2[nt];
            __half2 h0 = __floats2half2_rn(v[0] * rs, v[1] * rs);
            __half2 h1 = __floats2half2_rn(v[2] * rs, v[3] * rs);
            uint2 o;
            o.x = *(const unsigned int*)&h0;
            o.y = *(const unsigned int*)&h1;
            *(uint2*)(out + (size_t)row * 128 + n0) = o;
        }
    }
}

// ---------------- final aggregate F=128 ----------------
// h pre-scaled by dinv[src]; out[i] = relu(di*(h[i]+sum h[src]) + b), f32.
// 4 waves/block, 1 row per wave.
__global__ __launch_bounds__(256) void aggregate128_h_bias_relu(const __half* __restrict__ h,
                                                                const int* __restrict__ cnt,
                                                                const int* __restrict__ colFixed,
                                                                const float* __restrict__ bias,
                                                                float* __restrict__ out, int N) {
    const int lane = threadIdx.x & 63;
    const int i = blockIdx.x * 4 + (threadIdx.x >> 6);
    if (i >= N) return;
    const int degt = cnt[i];
    const float di = rsqrtf((float)(degt + 1));
    const int deg = (degt < CAP) ? degt : CAP;
    const unsigned int* __restrict__ hv = (const unsigned int*)h;  // half2 per slot
    float2 v = __half22float2(*(const __half2*)&hv[(size_t)i * 64 + lane]);
    float ax = v.x, ay = v.y;
    const int* __restrict__ cl = colFixed + (size_t)i * CAP;
    int e = 0;
    for (; e + 8 <= deg; e += 8) {
        int s[8];
#pragma unroll
        for (int j = 0; j < 8; ++j) s[j] = cl[e + j];
        unsigned int u[8];
#pragma unroll
        for (int j = 0; j < 8; ++j) u[j] = hv[(size_t)s[j] * 64 + lane];
#pragma unroll
        for (int j = 0; j < 8; ++j) {
            float2 g = __half22float2(*(const __half2*)&u[j]);
            ax += g.x;
            ay += g.y;
        }
    }
    for (; e < deg; ++e) {
        float2 g = __half22float2(*(const __half2*)&hv[(size_t)cl[e] * 64 + lane]);
        ax += g.x;
        ay += g.y;
    }
    float2 bb = ((const float2*)bias)[lane];
    float2 r;
    r.x = fmaxf(fmaf(ax, di, bb.x), 0.f);
    r.y = fmaxf(fmaf(ay, di, bb.y), 0.f);
    ((float2*)out)[(size_t)i * 64 + lane] = r;
}

extern "C" void kernel_launch(void* const* d_in, const int* in_sizes, int n_in,
                              void* d_out, int out_size, void* d_ws, size_t ws_size,
                              hipStream_t stream) {
    const float* x  = (const float*)d_in[0];
    const int*   ei = (const int*)d_in[1];
    const float* W1 = (const float*)d_in[2];
    const float* b1 = (const float*)d_in[3];
    const float* W2 = (const float*)d_in[4];
    const float* b2 = (const float*)d_in[5];
    float* out = (float*)d_out;

    const int N = in_sizes[0] / 256;
    const int E = in_sizes[1] / 2;
    const int* src = ei;
    const int* dst = ei + E;

    char* ws = (char*)d_ws;
    size_t off = 0;
    auto alloc = [&](size_t bytes) -> char* {
        char* p = ws + off;
        off += (bytes + 255) & ~(size_t)255;
        return p;
    };
    int*    cnt      = (int*)alloc((size_t)N * 4);
    int*    colFixed = (int*)alloc((size_t)N * CAP * 4);
    __half* Wp1      = (__half*)alloc((size_t)256 * 256 * 2);
    __half* Wp2      = (__half*)alloc((size_t)256 * 128 * 2);
    // bufA: xh (gather source, dead after agg256), then buf2h (gemm12 out)
    // bufB: buf1h (agg256 out, read by gemm12)
    __half* bufA     = (__half*)alloc((size_t)N * 256 * 2);
    __half* bufB     = (__half*)alloc((size_t)N * 256 * 2);
    __half* xh    = bufA;
    __half* buf2h = bufA;
    __half* buf1h = bufB;

    hipMemsetAsync(cnt, 0, (size_t)N * 4, stream);

    // prep: XCD-partitioned fill | pack xh | pack Wp1 | pack Wp2
    const int n8 = (N * 256) / 8;
    const int nbFill = 8 * ((E + FILL_CHUNK - 1) / FILL_CHUNK);
    const int nbPack = (n8 + 255) / 256;
    const int nbPrep = nbFill + nbPack + 32 + 16;
    prep_kernel<<<nbPrep, 256, 0, stream>>>(src, dst, E, cnt, colFixed, x, xh, n8,
                                            W1, Wp1, W2, Wp2, nbFill, nbPack);

    const int AB = (N + 3) / 4;     // 4 rows per block
    const int GB = (N + 63) / 64;   // 64 rows per block

    aggregate256_h<<<AB, 256, 0, stream>>>(xh, cnt, colFixed, buf1h, N);
    gemm12_lds<<<GB, 256, 0, stream>>>(buf1h, Wp1, b1, Wp2, cnt, buf2h, N);
    aggregate128_h_bias_relu<<<AB, 256, 0, stream>>>(buf2h, cnt, colFixed, b2, out, N);
}